// Round 2
// baseline (31300.089 us; speedup 1.0000x reference)
//
#include <hip/hip_runtime.h>
#include <math.h>

// Problem constants (from reference)
#define H_ 270
#define W_ 480
#define HW_ (H_ * W_)            // 129600
#define C_ 512
#define NC_ 19
#define N_ 32400
#define NP_ 32512                // N padded to multiple of 128
#define FULLPIX 2073600          // 1080*1920
#define K_ 9

// GEMM tiling: 64x128 block tile, thread = 2 rows x 16 cols (256 threads)
#define BM 64
#define BN 128
#define BK 16
#define NTILES (NP_ / BN)        // 254
#define CKS (C_ / BK)            // 32
#define JSPLIT 4                 // column-range split for occupancy
#define TILES_PER_PART 64        // ceil(254/4)

static_assert(NP_ % BN == 0, "pad");
static_assert(NP_ % BM == 0, "pad");
static_assert(C_ % BK == 0, "pad");

// ---------------------------------------------------------------------------
// Kernel A: gather sampled pixels into MT[C][NP] (K-major, coalesced writes).
__global__ void gather_kernel(const float* __restrict__ feat,
                              const int* __restrict__ sidx,
                              float* __restrict__ MT) {
    int i = blockIdx.x * 256 + threadIdx.x;   // 0..NP-1
    int c = blockIdx.y;
    float v = 0.0f;
    if (i < N_) v = feat[(size_t)c * HW_ + sidx[i]];
    MT[(size_t)c * NP_ + i] = v;
}

// ---------------------------------------------------------------------------
// Kernel B: per-sample squared norm. Pad entries get 1e30 (never selected).
__global__ void sq_kernel(const float* __restrict__ MT, float* __restrict__ fsq) {
    int i = blockIdx.x * 256 + threadIdx.x;
    float s = 0.0f;
    for (int c = 0; c < C_; ++c) {
        float v = MT[(size_t)c * NP_ + i];
        s = fmaf(v, v, s);
    }
    fsq[i] = (i < N_) ? s : 1e30f;
}

// ---------------------------------------------------------------------------
// Kernel C: predicted class = argmax over 19 channels (first-max like jnp.argmax)
__global__ void cls_kernel(const float* __restrict__ outs,
                           const int* __restrict__ sidx,
                           int* __restrict__ cls) {
    int i = blockIdx.x * 256 + threadIdx.x;
    if (i >= NP_) return;
    if (i >= N_) { cls[i] = 0; return; }
    int p = sidx[i];
    float best = outs[p];
    int bk = 0;
#pragma unroll
    for (int k = 1; k < NC_; ++k) {
        float v = outs[(size_t)k * HW_ + p];
        if (v > best) { best = v; bk = k; }   // strict > keeps first max
    }
    cls[i] = bk;
}

// ---------------------------------------------------------------------------
// Kernel D: fused Gram-GEMM + fully register-resident per-thread top-9.
// grid = 508*JSPLIT blocks, 256 threads. tx=tid&7 (16-col group), ty=tid>>3 (2-row group).
// Ranking key per row i: d' = fsq[j] - 2*dot(i,j)  (si + clamp don't affect order).
union SmU {
    struct { float As[2][BK][BM]; float Bs[2][BK * BN]; } st;  // 8KB + 16KB = 24KB
    struct { float md[BM][73]; int mi[BM][73]; } mg;           // 37.4KB (stride 73 -> 2-way reads)
};

#define FMA4(bv, n0)                                                        \
    acc[0][(n0) + 0] = fmaf(av.x, (bv).x, acc[0][(n0) + 0]);                \
    acc[1][(n0) + 0] = fmaf(av.y, (bv).x, acc[1][(n0) + 0]);                \
    acc[0][(n0) + 1] = fmaf(av.x, (bv).y, acc[0][(n0) + 1]);                \
    acc[1][(n0) + 1] = fmaf(av.y, (bv).y, acc[1][(n0) + 1]);                \
    acc[0][(n0) + 2] = fmaf(av.x, (bv).z, acc[0][(n0) + 2]);                \
    acc[1][(n0) + 2] = fmaf(av.y, (bv).z, acc[1][(n0) + 2]);                \
    acc[0][(n0) + 3] = fmaf(av.x, (bv).w, acc[0][(n0) + 3]);                \
    acc[1][(n0) + 3] = fmaf(av.y, (bv).w, acc[1][(n0) + 3]);

__launch_bounds__(256, 3)
__global__ void knn_kernel(const float* __restrict__ MT,
                           const float* __restrict__ fsq,
                           float* __restrict__ wd, int* __restrict__ wi) {
    __shared__ SmU sm;

    const int tid  = threadIdx.x;
    const int tx   = tid & 7;          // 0..7  col group (16 cols each)
    const int ty   = tid >> 3;         // 0..31 row group (2 rows each)
    const int part = blockIdx.x / 508; // same-part blocks adjacent -> share B-panel in L2
    const int rowb = blockIdx.x % 508;
    const int ibase = rowb * BM;

    const int t0 = part * TILES_PER_PART;
    const int t1 = min(t0 + TILES_PER_PART, NTILES);

    // staging roles
    const int akk  = tid >> 4;         // A: 0..15 row of tile
    const int aseg = tid & 15;         // A: 16B chunk
    const int bkk0 = tid >> 5;         // B chunk 0: 0..1
    const int bsg0 = tid & 31;
    const int bkk1 = (tid + 256) >> 5; // B chunk 1: 8..9
    const int bsg1 = bsg0;
    const int bpc0 = (bsg0 * 4) ^ (((bsg0 >> 3) & 3) << 2);  // XOR-swizzled B col
    const int bpc1 = bpc0;

    const int xv   = ((tx >> 1) & 3) << 2;   // read-side swizzle
    const int bcol = tx * 16;

    // two register-resident top-9 lists (rows ty*2, ty*2+1), sorted ascending
    float t9d[2][K_];
    int   t9i[2][K_];
#pragma unroll
    for (int m = 0; m < 2; ++m)
#pragma unroll
        for (int s = 0; s < K_; ++s) { t9d[m][s] = 1e38f; t9i[m][s] = 0x7fffffff; }
    float w90 = 1e38f, w91 = 1e38f;

    for (int jt = t0; jt < t1; ++jt) {
        const int jbase = jt * BN;
        float acc[2][16];
#pragma unroll
        for (int n = 0; n < 16; ++n) { acc[0][n] = 0.0f; acc[1][n] = 0.0f; }

        // prologue: stage ck=0 directly into buffer 0
        *(float4*)&sm.st.As[0][akk][aseg * 4] =
            *(const float4*)&MT[(size_t)akk * NP_ + ibase + aseg * 4];
        *(float4*)&sm.st.Bs[0][bkk0 * BN + bpc0] =
            *(const float4*)&MT[(size_t)bkk0 * NP_ + jbase + bsg0 * 4];
        *(float4*)&sm.st.Bs[0][bkk1 * BN + bpc1] =
            *(const float4*)&MT[(size_t)bkk1 * NP_ + jbase + bsg1 * 4];
        __syncthreads();

        int cur = 0;
        for (int ck = 0; ck < CKS; ++ck) {
            float4 ra, rb0, rb1;
            if (ck + 1 < CKS) {               // issue next-tile loads early (latency hides under kk loop)
                const int cc = (ck + 1) * BK;
                ra  = *(const float4*)&MT[(size_t)(cc + akk)  * NP_ + ibase + aseg * 4];
                rb0 = *(const float4*)&MT[(size_t)(cc + bkk0) * NP_ + jbase + bsg0 * 4];
                rb1 = *(const float4*)&MT[(size_t)(cc + bkk1) * NP_ + jbase + bsg1 * 4];
            }
#pragma unroll
            for (int kk = 0; kk < BK; ++kk) {
                float2 av = *(const float2*)&sm.st.As[cur][kk][ty * 2];
                const float* bb = &sm.st.Bs[cur][kk * BN];
                float4 b0 = *(const float4*)&bb[(bcol + 0)  ^ xv];
                float4 b1 = *(const float4*)&bb[(bcol + 4)  ^ xv];
                float4 b2 = *(const float4*)&bb[(bcol + 8)  ^ xv];
                float4 b3 = *(const float4*)&bb[(bcol + 12) ^ xv];
                FMA4(b0, 0) FMA4(b1, 4) FMA4(b2, 8) FMA4(b3, 12)
            }
            if (ck + 1 < CKS) {               // write prefetched tile to the other buffer
                const int nxt = cur ^ 1;
                *(float4*)&sm.st.As[nxt][akk][aseg * 4] = ra;
                *(float4*)&sm.st.Bs[nxt][bkk0 * BN + bpc0] = rb0;
                *(float4*)&sm.st.Bs[nxt][bkk1 * BN + bpc1] = rb1;
            }
            __syncthreads();
            cur ^= 1;
        }

        // epilogue: ranking key d' = sj - 2*acc, update register top-9 (ascending idx, strict <)
        float4 s0 = *(const float4*)&fsq[jbase + bcol + 0];
        float4 s1 = *(const float4*)&fsq[jbase + bcol + 4];
        float4 s2 = *(const float4*)&fsq[jbase + bcol + 8];
        float4 s3 = *(const float4*)&fsq[jbase + bcol + 12];
        float sj[16] = {s0.x, s0.y, s0.z, s0.w, s1.x, s1.y, s1.z, s1.w,
                        s2.x, s2.y, s2.z, s2.w, s3.x, s3.y, s3.z, s3.w};
        const int cb = jbase + bcol;
#pragma unroll
        for (int n = 0; n < 16; ++n) {
            float d0 = fmaf(-2.0f, acc[0][n], sj[n]);
            if (d0 < w90) {
                float cd = d0; int ci = cb + n;
#pragma unroll
                for (int s = 0; s < K_; ++s) {
                    bool sw = cd < t9d[0][s];
                    float td = t9d[0][s]; int ti = t9i[0][s];
                    t9d[0][s] = sw ? cd : td; t9i[0][s] = sw ? ci : ti;
                    cd = sw ? td : cd; ci = sw ? ti : ci;
                }
                w90 = t9d[0][K_ - 1];
            }
            float d1 = fmaf(-2.0f, acc[1][n], sj[n]);
            if (d1 < w91) {
                float cd = d1; int ci = cb + n;
#pragma unroll
                for (int s = 0; s < K_; ++s) {
                    bool sw = cd < t9d[1][s];
                    float td = t9d[1][s]; int ti = t9i[1][s];
                    t9d[1][s] = sw ? cd : td; t9i[1][s] = sw ? ci : ti;
                    cd = sw ? td : cd; ci = sw ? ti : ci;
                }
                w91 = t9d[1][K_ - 1];
            }
        }
    }

    // intra-block merge: 8 threads/row x 9 entries -> LDS (safe: last barrier drained all LDS reads)
#pragma unroll
    for (int m = 0; m < 2; ++m) {
        const int r = ty * 2 + m;
#pragma unroll
        for (int s = 0; s < K_; ++s) {
            sm.mg.md[r][tx * K_ + s] = t9d[m][s];
            sm.mg.mi[r][tx * K_ + s] = t9i[m][s];
        }
    }
    __syncthreads();
    if (tid < BM) {
        const int r = tid;
        float bd[K_]; int bx[K_];
#pragma unroll
        for (int s = 0; s < K_; ++s) { bd[s] = 1e38f; bx[s] = 0x7fffffff; }
        for (int e = 0; e < 8 * K_; ++e) {
            float cd = sm.mg.md[r][e];
            int   ci = sm.mg.mi[r][e];
#pragma unroll
            for (int s = 0; s < K_; ++s) {   // lex (d, idx): matches top_k lower-index-wins ties
                bool sw = (cd < bd[s]) || (cd == bd[s] && ci < bx[s]);
                float td = bd[s]; int ti = bx[s];
                bd[s] = sw ? cd : td; bx[s] = sw ? ci : ti;
                cd = sw ? td : cd; ci = sw ? ti : ci;
            }
        }
#pragma unroll
        for (int s = 0; s < K_; ++s) {       // coalesced: [part][s][row]
            wd[(size_t)(part * K_ + s) * NP_ + ibase + r] = bd[s];
            wi[(size_t)(part * K_ + s) * NP_ + ibase + r] = bx[s];
        }
    }
}

// ---------------------------------------------------------------------------
// Kernel E: merge JSPLIT partial top-9s -> entropy -> scatter.
__global__ void finalize_kernel(const float* __restrict__ wd, const int* __restrict__ wi,
                                const int* __restrict__ cls, const int* __restrict__ sidx,
                                float* __restrict__ out) {
    int i = blockIdx.x * 256 + threadIdx.x;
    if (i >= N_) return;
    float bd[K_]; int bx[K_];
#pragma unroll
    for (int s = 0; s < K_; ++s) { bd[s] = 1e38f; bx[s] = 0x7fffffff; }
#pragma unroll
    for (int p = 0; p < JSPLIT; ++p)
#pragma unroll
        for (int s = 0; s < K_; ++s) {
            float cd = wd[(size_t)(p * K_ + s) * NP_ + i];
            int   ci = wi[(size_t)(p * K_ + s) * NP_ + i];
#pragma unroll
            for (int t = 0; t < K_; ++t) {
                bool sw = (cd < bd[t]) || (cd == bd[t] && ci < bx[t]);
                float td = bd[t]; int ti = bx[t];
                bd[t] = sw ? cd : td; bx[t] = sw ? ci : ti;
                cd = sw ? td : cd; ci = sw ? ti : ci;
            }
        }
    int nb[K_];
#pragma unroll
    for (int s = 0; s < K_; ++s) nb[s] = cls[bx[s]];
    float ent = 0.0f;
#pragma unroll
    for (int k = 0; k < NC_; ++k) {
        int c = 0;
#pragma unroll
        for (int s = 0; s < K_; ++s) c += (nb[s] == k) ? 1 : 0;
        if (c > 0) {
            float p = (float)c / 9.0f;
            ent += -p * logf(p + 1e-6f);
        }
    }
    out[sidx[i]] = ent / 2.9444389791664403f;   // / np.float32(np.log(19))
}

// ---------------------------------------------------------------------------
// Kernel F: prototype-distance rank score (unchanged; passed round 1).
__global__ void proto_kernel(const float* __restrict__ MT,
                             const float* __restrict__ fsq,
                             const int* __restrict__ cls,
                             const int* __restrict__ sidx,
                             const float* __restrict__ protos,
                             float* __restrict__ out) {
    __shared__ float P[NC_][C_];
    __shared__ float psq[NC_];
    int tid = threadIdx.x;
    for (int idx = tid; idx < NC_ * C_; idx += 256)
        P[idx >> 9][idx & (C_ - 1)] = protos[idx];
    __syncthreads();
    if (tid < NC_) {
        float s = 0.0f;
        for (int c = 0; c < C_; ++c) { float v = P[tid][c]; s = fmaf(v, v, s); }
        psq[tid] = s;
    }
    __syncthreads();

    int i = blockIdx.x * 256 + tid;
    if (i >= N_) return;

    float accp[NC_];
#pragma unroll
    for (int k = 0; k < NC_; ++k) accp[k] = 0.0f;
    for (int c = 0; c < C_; ++c) {
        float f = MT[(size_t)c * NP_ + i];
#pragma unroll
        for (int k = 0; k < NC_; ++k) accp[k] = fmaf(f, P[k][c], accp[k]);
    }
    float s = fsq[i];
    int ci = cls[i];
    float dp[NC_];
    float dc = 0.0f;
#pragma unroll
    for (int k = 0; k < NC_; ++k) {
        float v = fmaxf(s - 2.0f * accp[k] + psq[k], 1e-12f);
        dp[k] = v;
        if (k == ci) dc = v;
    }
    int rank = 0;
#pragma unroll
    for (int k = 0; k < NC_; ++k) {
        rank += (dp[k] < dc) ? 1 : 0;
        rank += ((k < ci) && (dp[k] == dc)) ? 1 : 0;
    }
    out[FULLPIX + sidx[i]] = (float)rank / 18.0f;
}

// ---------------------------------------------------------------------------
extern "C" void kernel_launch(void* const* d_in, const int* in_sizes, int n_in,
                              void* d_out, int out_size, void* d_ws, size_t ws_size,
                              hipStream_t stream) {
    const float* feat   = (const float*)d_in[0];   // [1,512,270,480]
    const float* outs   = (const float*)d_in[1];   // [1,19,270,480]
    const float* protos = (const float*)d_in[2];   // [1,19,512]
    const int*   sidx   = (const int*)d_in[3];     // [32400] sorted
    float* out = (float*)d_out;                    // 2 x 2073600 f32

    // workspace layout (76.2 MB total)
    char* ws = (char*)d_ws;
    float* MT  = (float*)ws;                                    // 66,584,576 B
    float* fsq = (float*)(ws + 66584576ull);                    // 130,048 B
    int*   cls = (int*)  (ws + 66584576ull + 130048ull);        // 130,048 B
    float* wd  = (float*)(ws + 66844672ull);                    // 4,681,728 B
    int*   wi  = (int*)  (ws + 71526400ull);                    // 4,681,728 B

    hipMemsetAsync(d_out, 0, (size_t)2 * FULLPIX * sizeof(float), stream);

    gather_kernel<<<dim3(NP_ / 256, C_), 256, 0, stream>>>(feat, sidx, MT);
    sq_kernel<<<NP_ / 256, 256, 0, stream>>>(MT, fsq);
    cls_kernel<<<NP_ / 256, 256, 0, stream>>>(outs, sidx, cls);
    knn_kernel<<<508 * JSPLIT, 256, 0, stream>>>(MT, fsq, wd, wi);
    finalize_kernel<<<(N_ + 255) / 256, 256, 0, stream>>>(wd, wi, cls, sidx, out);
    proto_kernel<<<NP_ / 256, 256, 0, stream>>>(MT, fsq, cls, sidx, protos, out);
}